// Round 8
// baseline (3017.053 us; speedup 1.0000x reference)
//
#include <hip/hip_runtime.h>
#include <cfloat>

// Problem constants: B=16, N=8192, C=256; M derived from out_size (=2048).
// R8: third attempt at the coord-carry tail. R5 spilled (register arrays
// passed by pointer); R7 spilled (lambda capturing px2/py2/pz2 by reference
// -> alloca -> scratch, VGPR 48). Fix: NO lambda — the reduce tail is
// macro-inlined at both call sites so every array access is a static-index
// read in the kernel body (the exact pattern R0 allocated at 88 VGPR).
// Phase-2 coord fetch simplified: winning wave index = (wi>>6)&7 (uniform)
// -> direct readlane, no ballot/ffs.
#define BB 16
#define NN 8192
#define CC 256
#define NT 512                  // threads per FPS block (8 waves)
#define PPT 16                  // points per thread
#define NPAIR (PPT / 2)         // 8 packed f32x2 pairs
#define NWAVES (NT / 64)        // 8
#define TIT (1024 / NT)         // transpose float4 iters per 64x64 tile (=2)
#define TBLOCKS 240             // transpose helper blocks (fill idle CUs)
#define NTILES (BB * (CC / 64) * (NN / 64))   // 16*4*128 = 8192 64x64 tiles

typedef float    v2f __attribute__((ext_vector_type(2)));
typedef unsigned v2u __attribute__((ext_vector_type(2)));
typedef unsigned uu;
typedef unsigned long long ull;

// Barrier that waits ONLY on LDS (lgkmcnt), not vmcnt (wave 0's per-iter
// global stores need not retire before the barrier; drained at s_endpgm).
#define LDS_BARRIER() __asm__ __volatile__("s_waitcnt lgkmcnt(0)\n\ts_barrier" ::: "memory")

// Shared memory. FPS needs only the key/coord exchange slots (~0.5 KB);
// union with the transpose tile -> LDS block ~16.9 KB.
struct SmemFPS {
  ull    key[2][NWAVES];                  // double-buffered wave keys
  float4 kc[2][NWAVES];                   // winning candidate coords per wave
  float  red[NWAVES][3];
  float  ctr[3];
};
struct SmemT {
  float tile[64][65];                     // padded transpose tile
};
union Smem { SmemFPS f; SmemT t; };

// ---- guaranteed-packed f32 math (VOP3P). Each half is a plain IEEE f32 op
// (round-to-nearest-even), bit-identical to the scalar version. ----
__device__ __forceinline__ v2f pk_sub(v2f a, v2f b) {
  v2f d;
  asm("v_pk_add_f32 %0, %1, %2 neg_lo:[0,1] neg_hi:[0,1]"
      : "=v"(d) : "v"(a), "v"(b));
  return d;
}
__device__ __forceinline__ v2f pk_mul(v2f a, v2f b) {
  v2f d;
  asm("v_pk_mul_f32 %0, %1, %2" : "=v"(d) : "v"(a), "v"(b));
  return d;
}
__device__ __forceinline__ v2f pk_add(v2f a, v2f b) {
  v2f d;
  asm("v_pk_add_f32 %0, %1, %2" : "=v"(d) : "v"(a), "v"(b));
  return d;
}

__device__ __forceinline__ uu umin2(uu a, uu b) { return a < b ? a : b; }
__device__ __forceinline__ uu umax2(uu a, uu b) { return a > b ? a : b; }

// key = (dist_bits << 32) | ~index. dist >= 0 -> u32 bit order == f32 order.
// max key = max dist; tie -> larger ~idx = smaller idx = numpy first-occurrence.
__device__ __forceinline__ ull max64(ull a, ull b) { return a > b ? a : b; }

// One DPP max step on a u64 key (both 32-bit halves move with same pattern).
template <int CTRL>
__device__ __forceinline__ ull dpp_max64(ull x) {
  int lo = (int)(uu)x;
  int hi = (int)(uu)(x >> 32);
  int plo = __builtin_amdgcn_update_dpp(0, lo, CTRL, 0xF, 0xF, true);
  int phi = __builtin_amdgcn_update_dpp(0, hi, CTRL, 0xF, 0xF, true);
  ull p = ((ull)(uu)phi << 32) | (uu)plo;
  return max64(x, p);
}

// Wave64 max funneled into lane 63, all on the VALU pipe (no LDS-pipe ops).
__device__ __forceinline__ ull wave_max63(ull k) {
  k = dpp_max64<0xB1>(k);    // quad_perm xor1
  k = dpp_max64<0x4E>(k);    // quad_perm xor2
  k = dpp_max64<0x124>(k);   // row_ror:4
  k = dpp_max64<0x128>(k);   // row_ror:8 -> full 16-lane row max
  k = dpp_max64<0x142>(k);   // row_bcast15
  k = dpp_max64<0x143>(k);   // row_bcast31 -> lane 63 has wave max
  return k;
}

__device__ __forceinline__ float bcast_lane(float v, int src) {
  return __int_as_float(__builtin_amdgcn_readlane(__float_as_int(v), src));
}

// Macro-inlined reduce tail (NO lambda/function boundary -> px2/py2/pz2 stay
// in registers). Inputs: VV (u32 max dist bits), BKK (int candidate slot).
// Outputs (kernel-scope locals): wi, wx, wy, wz. Uses: t, wave, lane, ep, sm,
// px2, py2, pz2.
// Phase 1: wave key reduce (6 DPP), readlane(63) broadcast; the ONE winning
//   lane per wave (execz-skips the other 7 waves' mux+write) muxes its
//   candidate coords (static indices) and writes key(b64)+coords(b128).
// Phase 2 (after one lgkm barrier): spread b64+b128 read, 3 DPP key steps,
//   then readlane((wi>>6)&7) pulls the winner coords -> no second LDS trip.
#define REDUCE_TAIL(VV, BKK)                                                   \
  {                                                                            \
    ull rt_key = ((ull)(VV) << 32) | (uu)(~(uu)(t + (BKK) * NT));              \
    ull rt_wk = wave_max63(rt_key);                                            \
    ep ^= 1;                                                                   \
    uu rt_lo = (uu)__builtin_amdgcn_readlane((int)(uu)rt_wk, 63);              \
    uu rt_hi = (uu)__builtin_amdgcn_readlane((int)(uu)(rt_wk >> 32), 63);      \
    ull rt_wmax = ((ull)rt_hi << 32) | rt_lo;                                  \
    if (rt_key == rt_wmax) {                                                   \
      float rt_qx = 0.f, rt_qy = 0.f, rt_qz = 0.f;                             \
      _Pragma("unroll")                                                        \
      for (int rt_k = 0; rt_k < PPT; ++rt_k) {                                 \
        if ((BKK) == rt_k) {                                                   \
          rt_qx = (rt_k & 1) ? px2[rt_k >> 1].y : px2[rt_k >> 1].x;            \
          rt_qy = (rt_k & 1) ? py2[rt_k >> 1].y : py2[rt_k >> 1].x;            \
          rt_qz = (rt_k & 1) ? pz2[rt_k >> 1].y : pz2[rt_k >> 1].x;            \
        }                                                                      \
      }                                                                        \
      sm.f.key[ep][wave] = rt_key;                                             \
      sm.f.kc[ep][wave] = make_float4(rt_qx, rt_qy, rt_qz, 0.f);               \
    }                                                                          \
    LDS_BARRIER();                                                             \
    ull rt_kk = sm.f.key[ep][lane & 7];                                        \
    float4 rt_cc = sm.f.kc[ep][lane & 7];                                      \
    rt_kk = dpp_max64<0xB1>(rt_kk);                                            \
    rt_kk = dpp_max64<0x4E>(rt_kk);                                            \
    rt_kk = dpp_max64<0x124>(rt_kk);                                           \
    wi = (int)~(uu)rt_kk;                                                      \
    int rt_src = (wi >> 6) & 7;    /* winning wave id; uniform */              \
    wx = bcast_lane(rt_cc.x, rt_src);                                          \
    wy = bcast_lane(rt_cc.y, rt_src);                                          \
    wz = bcast_lane(rt_cc.z, rt_src);                                          \
  }

// blockIdx < BB: one FPS workgroup per batch.
// blockIdx >= BB (when do_trans): grid-stride transpose of features
// [B][C][N] -> trans [B][N][C], hidden under FPS on the idle 240 CUs.
__global__ __launch_bounds__(NT)
void fps_fused_kernel(const float* __restrict__ pts,
                      const float* __restrict__ feats,
                      float* __restrict__ out_pts,
                      int* __restrict__ idx_out,
                      float* __restrict__ trans, int M, int do_trans) {
  __shared__ Smem sm;
  const int t = threadIdx.x;

  if (blockIdx.x >= BB) {
    // ---------------- transpose path (unchanged from R0) ----------------
    if (!do_trans) return;
    for (int tileId = blockIdx.x - BB; tileId < NTILES; tileId += TBLOCKS) {
      int b  = tileId / ((CC / 64) * (NN / 64));
      int r  = tileId % ((CC / 64) * (NN / 64));
      int ct = r / (NN / 64);           // c-tile 0..3
      int nt = r % (NN / 64);           // n-tile 0..127
      const float* src = feats + ((size_t)b * CC + ct * 64) * NN + nt * 64;
      float* dst = trans + ((size_t)b * NN + nt * 64) * CC + ct * 64;
#pragma unroll
      for (int i = 0; i < TIT; ++i) {   // 1024 float4 loads total per tile
        int f = t + i * NT;
        int c = f >> 4, n4 = f & 15;
        float4 v = *(const float4*)(src + (size_t)c * NN + n4 * 4);
        sm.t.tile[c][n4 * 4 + 0] = v.x;
        sm.t.tile[c][n4 * 4 + 1] = v.y;
        sm.t.tile[c][n4 * 4 + 2] = v.z;
        sm.t.tile[c][n4 * 4 + 3] = v.w;
      }
      __syncthreads();
#pragma unroll
      for (int i = 0; i < TIT; ++i) {
        int f = t + i * NT;
        int n = f >> 4, c4 = f & 15;
        float4 o;
        o.x = sm.t.tile[c4 * 4 + 0][n];
        o.y = sm.t.tile[c4 * 4 + 1][n];
        o.z = sm.t.tile[c4 * 4 + 2][n];
        o.w = sm.t.tile[c4 * 4 + 3][n];
        *(float4*)(dst + (size_t)n * CC + c4 * 4) = o;
      }
      __syncthreads();                  // tile reuse across grid-stride iters
    }
    return;
  }

  // ---------------- FPS path ----------------
  const int b = blockIdx.x;
  const int wave = t >> 6;
  const int lane = t & 63;
  const float* base = pts + (size_t)b * 3 * NN;   // [3][N] for this batch

  v2f px2[NPAIR], py2[NPAIR], pz2[NPAIR];
  v2u dist2[NPAIR];
  const uu INIT = __float_as_uint(1e10f);         // matches jnp.full(1e10)
#pragma unroll
  for (int j = 0; j < NPAIR; ++j) {
    int n0 = t + (2 * j) * NT;                    // coalesced loads
    int n1 = t + (2 * j + 1) * NT;
    float x0 = base[n0], y0 = base[NN + n0], z0 = base[2 * NN + n0];
    float x1 = base[n1], y1 = base[NN + n1], z1 = base[2 * NN + n1];
    px2[j] = (v2f){x0, x1};
    py2[j] = (v2f){y0, y1};
    pz2[j] = (v2f){z0, z1};
    dist2[j] = (v2u){INIT, INIT};
  }

  // ---- centroid (one-time; latency irrelevant; standard barriers OK) ----
  float sx = 0.f, sy = 0.f, sz = 0.f;
#pragma unroll
  for (int j = 0; j < NPAIR; ++j) {
    sx += px2[j].x; sx += px2[j].y;
    sy += py2[j].x; sy += py2[j].y;
    sz += pz2[j].x; sz += pz2[j].y;
  }
#pragma unroll
  for (int off = 32; off > 0; off >>= 1) {
    sx += __shfl_xor(sx, off);
    sy += __shfl_xor(sy, off);
    sz += __shfl_xor(sz, off);
  }
  if (lane == 0) { sm.f.red[wave][0] = sx; sm.f.red[wave][1] = sy; sm.f.red[wave][2] = sz; }
  __syncthreads();
  if (t == 0) {
    float gx = 0.f, gy = 0.f, gz = 0.f;
    for (int w = 0; w < NWAVES; ++w) { gx += sm.f.red[w][0]; gy += sm.f.red[w][1]; gz += sm.f.red[w][2]; }
    sm.f.ctr[0] = gx / NN; sm.f.ctr[1] = gy / NN; sm.f.ctr[2] = gz / NN;  // /8192 exact
  }
  __syncthreads();
  const float ctx = sm.f.ctr[0], cty = sm.f.ctr[1], ctz = sm.f.ctr[2];

  int ep = 0;        // key epoch (parity double-buffer -> one barrier per iter)
  int   wi;          // winning global index
  float wx, wy, wz;  // winning coords (registers after phase 2)

  // ---- initial farthest = argmax of dist-to-centroid (no dist update) ----
  {
    v2f c2x = {ctx, ctx}, c2y = {cty, cty}, c2z = {ctz, ctz};
    v2u nd2[NPAIR];
    uu v = 0u;
#pragma unroll
    for (int j = 0; j < NPAIR; ++j) {
      v2f dx = pk_sub(px2[j], c2x);
      v2f dy = pk_sub(py2[j], c2y);
      v2f dz = pk_sub(pz2[j], c2z);
      // exact numpy order: ((dx*dx + dy*dy) + dz*dz), no FMA
      v2f d = pk_add(pk_add(pk_mul(dx, dx), pk_mul(dy, dy)), pk_mul(dz, dz));
      v2u du = (v2u){__float_as_uint(d.x), __float_as_uint(d.y)};
      nd2[j] = du;
      v = umax2(v, umax2(du.x, du.y));           // v_max3_u32
    }
    int bk = 0;
#pragma unroll
    for (int k = PPT - 1; k >= 0; --k) {         // descending: keeps smallest k
      uu ndk = (k & 1) ? nd2[k >> 1].y : nd2[k >> 1].x;
      if (ndk == v) bk = k;                      // first-occurrence tie-break
    }
    REDUCE_TAIL(v, bk);
  }

  // ---- FPS main loop ----
  for (int m = 0; m < M; ++m) {
    float cx = wx, cy = wy, cz = wz;             // winner coords: registers
    if (t == 0) {
      idx_out[b * M + m] = wi;
      size_t o = ((size_t)b * M + m) * 3;
      out_pts[o] = cx; out_pts[o + 1] = cy; out_pts[o + 2] = cz;
    }
    if (m == M - 1) break;

    v2f c2x = {cx, cx}, c2y = {cy, cy}, c2z = {cz, cz};
    uu v = 0u;
#pragma unroll
    for (int j = 0; j < NPAIR; ++j) {
      v2f dx = pk_sub(px2[j], c2x);
      v2f dy = pk_sub(py2[j], c2y);
      v2f dz = pk_sub(pz2[j], c2z);
      v2f d = pk_add(pk_add(pk_mul(dx, dx), pk_mul(dy, dy)), pk_mul(dz, dz));
      // dists >= 0 -> u32 min/max on the bits == f32 min/max
      v2u nd;
      nd.x = umin2(dist2[j].x, __float_as_uint(d.x));
      nd.y = umin2(dist2[j].y, __float_as_uint(d.y));
      dist2[j] = nd;                     // updated in place
      v = umax2(v, umax2(nd.x, nd.y));   // v_max3_u32 chain
    }
    int bk = 0;
#pragma unroll
    for (int k = PPT - 1; k >= 0; --k) {
      uu ndk = (k & 1) ? dist2[k >> 1].y : dist2[k >> 1].x;
      if (ndk == v) bk = k;
    }
    REDUCE_TAIL(v, bk);
  }
}

// Gather from transposed features: fully coalesced float4 both sides.
__global__ __launch_bounds__(256)
void gather_t_kernel(const float* __restrict__ trans,
                     const int* __restrict__ idx,
                     float* __restrict__ out_f, int M) {
  int gm = blockIdx.x * 4 + (threadIdx.x >> 6);
  if (gm >= BB * M) return;
  int lane = threadIdx.x & 63;
  int b = gm / M;
  int n = idx[gm];
  float4 v = *(const float4*)(trans + ((size_t)b * NN + n) * CC + lane * 4);
  *(float4*)(out_f + (size_t)gm * CC + lane * 4) = v;
}

// Fallback gather (ws too small for transpose): scattered reads, L2/L3-bound.
__global__ __launch_bounds__(CC)
void gather_kernel(const float* __restrict__ feats, const int* __restrict__ idx,
                   float* __restrict__ out_f, int M) {
  const int bm = blockIdx.x;
  const int b = bm / M;
  const int n = idx[bm];
  const int c = threadIdx.x;
  out_f[(size_t)bm * CC + c] = feats[((size_t)b * CC + c) * NN + n];
}

extern "C" void kernel_launch(void* const* d_in, const int* in_sizes, int n_in,
                              void* d_out, int out_size, void* d_ws, size_t ws_size,
                              hipStream_t stream) {
  const float* points = (const float*)d_in[0];   // [B,3,N] f32
  const float* feats  = (const float*)d_in[1];   // [B,C,N] f32
  // out_size = B*M*3 + B*M*C = M * B * (3+C)
  int M = out_size / (BB * (3 + CC));            // = 2048
  if (M <= 0) M = 1;

  float* out_pts = (float*)d_out;                        // [B,M,3]
  float* out_f   = (float*)d_out + (size_t)BB * M * 3;   // [B,M,C]

  int* idx_ws = (int*)d_ws;                              // B*M ints
  size_t idx_bytes = (((size_t)BB * M * sizeof(int)) + 255) & ~(size_t)255;
  size_t trans_bytes = (size_t)BB * NN * CC * sizeof(float);   // 134.2 MB
  bool use_t = (ws_size >= idx_bytes + trans_bytes);
  float* trans = (float*)((char*)d_ws + idx_bytes);

  int grid = use_t ? (BB + TBLOCKS) : BB;
  fps_fused_kernel<<<dim3(grid), dim3(NT), 0, stream>>>(
      points, feats, out_pts, idx_ws, trans, M, use_t ? 1 : 0);

  if (use_t) {
    gather_t_kernel<<<dim3((BB * M + 3) / 4), dim3(256), 0, stream>>>(
        trans, idx_ws, out_f, M);
  } else {
    gather_kernel<<<dim3(BB * M), dim3(CC), 0, stream>>>(feats, idx_ws, out_f, M);
  }
}

// Round 9
// 1991.512 us; speedup vs baseline: 1.5150x; 1.5150x over previous
//
#include <hip/hip_runtime.h>
#include <cfloat>

// Problem constants: B=16, N=8192, C=256; M derived from out_size (=2048).
// R9: back to R0's proven structure (LDS coord mirror; 88 VGPR; 1757us) after
// the coord-carry tail spilled in 3 different forms (R5/R7/R8 all VGPR<=56:
// any tail that reads px2/py2/pz2 gets the arrays demoted to scratch).
// Two chain-shorteners that never touch the point arrays from the tail:
//  (1) key-tree: per-thread argmax via a depth-4 max-tree over 16 u64 keys
//      (dist_bits<<32 | ~idx) -- replaces the v-max chain + 16-step scan
//      (~96-cyc chain -> ~24), identical tie-break semantics.
//  (2) phase-2 speculative coord prefetch: after the spread key read each
//      lane reads the MIRROR at wave(lane&7)'s candidate while the 3 block
//      DPP steps run; winner coords then come from readlane((wi>>6)&7)
//      (pattern proven correct in R8) -- removes the dependent top-of-loop
//      coord broadcast read.
#define BB 16
#define NN 8192
#define CC 256
#define NT 512                  // threads per FPS block (8 waves; measured opt)
#define PPT 16                  // points per thread
#define NPAIR (PPT / 2)         // 8 packed f32x2 pairs
#define NWAVES (NT / 64)        // 8
#define TIT (1024 / NT)         // transpose float4 iters per 64x64 tile (=2)
#define TBLOCKS 240             // transpose helper blocks (fill idle CUs)
#define NTILES (BB * (CC / 64) * (NN / 64))   // 16*4*128 = 8192 64x64 tiles

typedef float    v2f __attribute__((ext_vector_type(2)));
typedef unsigned v2u __attribute__((ext_vector_type(2)));
typedef unsigned uu;
typedef unsigned long long ull;

// Barrier that waits ONLY on LDS (lgkmcnt), not vmcnt (wave 0's per-iter
// global stores need not retire before the barrier; drained at s_endpgm).
#define LDS_BARRIER() __asm__ __volatile__("s_waitcnt lgkmcnt(0)\n\ts_barrier" ::: "memory")

// Shared memory. FPS view: separate x/y/z coord arrays -> candidate fetch is
// b32 broadcast-group reads (conflict-light). Union with the transpose tile.
// NOTE (R0 measured): SQ_LDS_BANK_CONFLICT == 2^21 comes from the transpose
// tile's 2-way aliasing (benign per m136), NOT from the FPS path.
struct SmemFPS {
  float px[NN], py[NN], pz[NN];           // 96 KB point mirror
  ull   key[2][NWAVES];                   // double-buffered wave keys
  float red[NWAVES][3];
  float ctr[3];
};
struct SmemT {
  float tile[64][65];                     // padded transpose tile
};
union Smem { SmemFPS f; SmemT t; };

// ---- guaranteed-packed f32 math (VOP3P). Each half is a plain IEEE f32 op
// (round-to-nearest-even), bit-identical to the scalar version. ----
__device__ __forceinline__ v2f pk_sub(v2f a, v2f b) {
  v2f d;
  asm("v_pk_add_f32 %0, %1, %2 neg_lo:[0,1] neg_hi:[0,1]"
      : "=v"(d) : "v"(a), "v"(b));
  return d;
}
__device__ __forceinline__ v2f pk_mul(v2f a, v2f b) {
  v2f d;
  asm("v_pk_mul_f32 %0, %1, %2" : "=v"(d) : "v"(a), "v"(b));
  return d;
}
__device__ __forceinline__ v2f pk_add(v2f a, v2f b) {
  v2f d;
  asm("v_pk_add_f32 %0, %1, %2" : "=v"(d) : "v"(a), "v"(b));
  return d;
}

__device__ __forceinline__ uu umin2(uu a, uu b) { return a < b ? a : b; }

// key = (dist_bits << 32) | ~index. dist >= 0 -> u32 bit order == f32 order.
// max key = max dist; tie -> larger ~idx = smaller idx = numpy first-occurrence.
__device__ __forceinline__ ull max64(ull a, ull b) { return a > b ? a : b; }

// One DPP max step on a u64 key (both 32-bit halves move with same pattern).
template <int CTRL>
__device__ __forceinline__ ull dpp_max64(ull x) {
  int lo = (int)(uu)x;
  int hi = (int)(uu)(x >> 32);
  int plo = __builtin_amdgcn_update_dpp(0, lo, CTRL, 0xF, 0xF, true);
  int phi = __builtin_amdgcn_update_dpp(0, hi, CTRL, 0xF, 0xF, true);
  ull p = ((ull)(uu)phi << 32) | (uu)plo;
  return max64(x, p);
}

// Wave64 max funneled into lane 63, all on the VALU pipe (no LDS-pipe ops).
__device__ __forceinline__ ull wave_max63(ull k) {
  k = dpp_max64<0xB1>(k);    // quad_perm xor1
  k = dpp_max64<0x4E>(k);    // quad_perm xor2
  k = dpp_max64<0x124>(k);   // row_ror:4
  k = dpp_max64<0x128>(k);   // row_ror:8 -> full 16-lane row max
  k = dpp_max64<0x142>(k);   // row_bcast15
  k = dpp_max64<0x143>(k);   // row_bcast31 -> lane 63 has wave max
  return k;
}

__device__ __forceinline__ float bcast_lane(float v, int src) {
  return __int_as_float(__builtin_amdgcn_readlane(__float_as_int(v), src));
}

// Reduce tail. Input: MYKEY (u64). Outputs (kernel-scope): wi, wx, wy, wz.
// Phase 1: 6-DPP wave key reduce, lane-63 key write (b64), ONE lgkm barrier.
// Phase 2: spread key read; each lane immediately issues 3 speculative
//   mirror reads at wave(lane&7)'s candidate index (overlaps the 3 block
//   DPP steps); winner coords via readlane((wi>>6)&7). No array accesses ->
//   no scratch-demotion risk (R5/R7/R8 lesson).
#define REDUCE_TAIL2(MYKEY)                                                    \
  {                                                                            \
    ull rt_w = wave_max63(MYKEY);                                              \
    ep ^= 1;                                                                   \
    if (lane == 63) sm.f.key[ep][wave] = rt_w;                                 \
    LDS_BARRIER();                                                             \
    ull rt_kk = sm.f.key[ep][lane & 7];   /* spread b64 read */                \
    uu rt_cand = ~(uu)rt_kk;              /* wave (lane&7)'s candidate */      \
    float rt_qx = sm.f.px[rt_cand];       /* speculative: overlaps DPPs */     \
    float rt_qy = sm.f.py[rt_cand];                                            \
    float rt_qz = sm.f.pz[rt_cand];                                            \
    rt_kk = dpp_max64<0xB1>(rt_kk);       /* xor1 within 8-key group */        \
    rt_kk = dpp_max64<0x4E>(rt_kk);       /* xor2 */                           \
    rt_kk = dpp_max64<0x124>(rt_kk);      /* row_ror:4 -> all-8 max */         \
    wi = (int)~(uu)rt_kk;                                                      \
    int rt_src = (wi >> 6) & 7;           /* winning wave id; uniform */       \
    wx = bcast_lane(rt_qx, rt_src);                                            \
    wy = bcast_lane(rt_qy, rt_src);                                            \
    wz = bcast_lane(rt_qz, rt_src);                                            \
  }

// blockIdx < BB: one FPS workgroup per batch.
// blockIdx >= BB (when do_trans): grid-stride transpose of features
// [B][C][N] -> trans [B][N][C], hidden under FPS on the idle 240 CUs.
__global__ __launch_bounds__(NT)
void fps_fused_kernel(const float* __restrict__ pts,
                      const float* __restrict__ feats,
                      float* __restrict__ out_pts,
                      int* __restrict__ idx_out,
                      float* __restrict__ trans, int M, int do_trans) {
  __shared__ Smem sm;
  const int t = threadIdx.x;

  if (blockIdx.x >= BB) {
    // ---------------- transpose path (unchanged from R0) ----------------
    if (!do_trans) return;
    for (int tileId = blockIdx.x - BB; tileId < NTILES; tileId += TBLOCKS) {
      int b  = tileId / ((CC / 64) * (NN / 64));
      int r  = tileId % ((CC / 64) * (NN / 64));
      int ct = r / (NN / 64);           // c-tile 0..3
      int nt = r % (NN / 64);           // n-tile 0..127
      const float* src = feats + ((size_t)b * CC + ct * 64) * NN + nt * 64;
      float* dst = trans + ((size_t)b * NN + nt * 64) * CC + ct * 64;
#pragma unroll
      for (int i = 0; i < TIT; ++i) {   // 1024 float4 loads total per tile
        int f = t + i * NT;
        int c = f >> 4, n4 = f & 15;
        float4 v = *(const float4*)(src + (size_t)c * NN + n4 * 4);
        sm.t.tile[c][n4 * 4 + 0] = v.x;
        sm.t.tile[c][n4 * 4 + 1] = v.y;
        sm.t.tile[c][n4 * 4 + 2] = v.z;
        sm.t.tile[c][n4 * 4 + 3] = v.w;
      }
      __syncthreads();
#pragma unroll
      for (int i = 0; i < TIT; ++i) {
        int f = t + i * NT;
        int n = f >> 4, c4 = f & 15;
        float4 o;
        o.x = sm.t.tile[c4 * 4 + 0][n];
        o.y = sm.t.tile[c4 * 4 + 1][n];
        o.z = sm.t.tile[c4 * 4 + 2][n];
        o.w = sm.t.tile[c4 * 4 + 3][n];
        *(float4*)(dst + (size_t)n * CC + c4 * 4) = o;
      }
      __syncthreads();                  // tile reuse across grid-stride iters
    }
    return;
  }

  // ---------------- FPS path ----------------
  const int b = blockIdx.x;
  const int wave = t >> 6;
  const int lane = t & 63;
  const float* base = pts + (size_t)b * 3 * NN;   // [3][N] for this batch

  v2f px2[NPAIR], py2[NPAIR], pz2[NPAIR];
  v2u dist2[NPAIR];
  const uu INIT = __float_as_uint(1e10f);         // matches jnp.full(1e10)
#pragma unroll
  for (int j = 0; j < NPAIR; ++j) {
    int n0 = t + (2 * j) * NT;                    // coalesced loads
    int n1 = t + (2 * j + 1) * NT;
    float x0 = base[n0], y0 = base[NN + n0], z0 = base[2 * NN + n0];
    float x1 = base[n1], y1 = base[NN + n1], z1 = base[2 * NN + n1];
    px2[j] = (v2f){x0, x1};
    py2[j] = (v2f){y0, y1};
    pz2[j] = (v2f){z0, z1};
    sm.f.px[n0] = x0; sm.f.py[n0] = y0; sm.f.pz[n0] = z0;
    sm.f.px[n1] = x1; sm.f.py[n1] = y1; sm.f.pz[n1] = z1;
    dist2[j] = (v2u){INIT, INIT};
  }

  // per-slot inverted global index constants: key low word
  uu ii[PPT];
#pragma unroll
  for (int k = 0; k < PPT; ++k) ii[k] = ~(uu)(t + k * NT);

  // ---- centroid (one-time; latency irrelevant; standard barriers OK) ----
  float sx = 0.f, sy = 0.f, sz = 0.f;
#pragma unroll
  for (int j = 0; j < NPAIR; ++j) {
    sx += px2[j].x; sx += px2[j].y;
    sy += py2[j].x; sy += py2[j].y;
    sz += pz2[j].x; sz += pz2[j].y;
  }
#pragma unroll
  for (int off = 32; off > 0; off >>= 1) {
    sx += __shfl_xor(sx, off);
    sy += __shfl_xor(sy, off);
    sz += __shfl_xor(sz, off);
  }
  if (lane == 0) { sm.f.red[wave][0] = sx; sm.f.red[wave][1] = sy; sm.f.red[wave][2] = sz; }
  __syncthreads();    // also covers coord-mirror staging writes
  if (t == 0) {
    float gx = 0.f, gy = 0.f, gz = 0.f;
    for (int w = 0; w < NWAVES; ++w) { gx += sm.f.red[w][0]; gy += sm.f.red[w][1]; gz += sm.f.red[w][2]; }
    sm.f.ctr[0] = gx / NN; sm.f.ctr[1] = gy / NN; sm.f.ctr[2] = gz / NN;  // /8192 exact
  }
  __syncthreads();
  const float ctx = sm.f.ctr[0], cty = sm.f.ctr[1], ctz = sm.f.ctr[2];

  int ep = 0;        // key epoch (parity double-buffer -> one barrier per iter)
  int   wi;          // winning global index
  float wx, wy, wz;  // winning coords (registers after phase 2)

  // ---- initial farthest = argmax of dist-to-centroid (no dist update) ----
  {
    v2f c2x = {ctx, ctx}, c2y = {cty, cty}, c2z = {ctz, ctz};
    ull kreg[PPT];
#pragma unroll
    for (int j = 0; j < NPAIR; ++j) {
      v2f dx = pk_sub(px2[j], c2x);
      v2f dy = pk_sub(py2[j], c2y);
      v2f dz = pk_sub(pz2[j], c2z);
      // exact numpy order: ((dx*dx + dy*dy) + dz*dz), no FMA
      v2f d = pk_add(pk_add(pk_mul(dx, dx), pk_mul(dy, dy)), pk_mul(dz, dz));
      kreg[2 * j]     = ((ull)__float_as_uint(d.x) << 32) | ii[2 * j];
      kreg[2 * j + 1] = ((ull)__float_as_uint(d.y) << 32) | ii[2 * j + 1];
    }
#pragma unroll
    for (int s = 1; s < PPT; s <<= 1) {
#pragma unroll
      for (int k = 0; k + s < PPT; k += 2 * s) kreg[k] = max64(kreg[k], kreg[k + s]);
    }
    REDUCE_TAIL2(kreg[0]);
  }

  // ---- FPS main loop ----
  for (int m = 0; m < M; ++m) {
    float cx = wx, cy = wy, cz = wz;             // winner coords: registers
    if (t == 0) {
      idx_out[b * M + m] = wi;
      size_t o = ((size_t)b * M + m) * 3;
      out_pts[o] = cx; out_pts[o + 1] = cy; out_pts[o + 2] = cz;
    }
    if (m == M - 1) break;

    v2f c2x = {cx, cx}, c2y = {cy, cy}, c2z = {cz, cz};
    ull kreg[PPT];
#pragma unroll
    for (int j = 0; j < NPAIR; ++j) {
      v2f dx = pk_sub(px2[j], c2x);
      v2f dy = pk_sub(py2[j], c2y);
      v2f dz = pk_sub(pz2[j], c2z);
      v2f d = pk_add(pk_add(pk_mul(dx, dx), pk_mul(dy, dy)), pk_mul(dz, dz));
      // dists >= 0 -> u32 min on the bits == f32 min
      v2u nd;
      nd.x = umin2(dist2[j].x, __float_as_uint(d.x));
      nd.y = umin2(dist2[j].y, __float_as_uint(d.y));
      dist2[j] = nd;
      kreg[2 * j]     = ((ull)nd.x << 32) | ii[2 * j];
      kreg[2 * j + 1] = ((ull)nd.y << 32) | ii[2 * j + 1];
    }
#pragma unroll
    for (int s = 1; s < PPT; s <<= 1) {
#pragma unroll
      for (int k = 0; k + s < PPT; k += 2 * s) kreg[k] = max64(kreg[k], kreg[k + s]);
    }
    REDUCE_TAIL2(kreg[0]);
  }
}

// Gather from transposed features: fully coalesced float4 both sides.
__global__ __launch_bounds__(256)
void gather_t_kernel(const float* __restrict__ trans,
                     const int* __restrict__ idx,
                     float* __restrict__ out_f, int M) {
  int gm = blockIdx.x * 4 + (threadIdx.x >> 6);
  if (gm >= BB * M) return;
  int lane = threadIdx.x & 63;
  int b = gm / M;
  int n = idx[gm];
  float4 v = *(const float4*)(trans + ((size_t)b * NN + n) * CC + lane * 4);
  *(float4*)(out_f + (size_t)gm * CC + lane * 4) = v;
}

// Fallback gather (ws too small for transpose): scattered reads, L2/L3-bound.
__global__ __launch_bounds__(CC)
void gather_kernel(const float* __restrict__ feats, const int* __restrict__ idx,
                   float* __restrict__ out_f, int M) {
  const int bm = blockIdx.x;
  const int b = bm / M;
  const int n = idx[bm];
  const int c = threadIdx.x;
  out_f[(size_t)bm * CC + c] = feats[((size_t)b * CC + c) * NN + n];
}

extern "C" void kernel_launch(void* const* d_in, const int* in_sizes, int n_in,
                              void* d_out, int out_size, void* d_ws, size_t ws_size,
                              hipStream_t stream) {
  const float* points = (const float*)d_in[0];   // [B,3,N] f32
  const float* feats  = (const float*)d_in[1];   // [B,C,N] f32
  // out_size = B*M*3 + B*M*C = M * B * (3+C)
  int M = out_size / (BB * (3 + CC));            // = 2048
  if (M <= 0) M = 1;

  float* out_pts = (float*)d_out;                        // [B,M,3]
  float* out_f   = (float*)d_out + (size_t)BB * M * 3;   // [B,M,C]

  int* idx_ws = (int*)d_ws;                              // B*M ints
  size_t idx_bytes = (((size_t)BB * M * sizeof(int)) + 255) & ~(size_t)255;
  size_t trans_bytes = (size_t)BB * NN * CC * sizeof(float);   // 134.2 MB
  bool use_t = (ws_size >= idx_bytes + trans_bytes);
  float* trans = (float*)((char*)d_ws + idx_bytes);

  int grid = use_t ? (BB + TBLOCKS) : BB;
  fps_fused_kernel<<<dim3(grid), dim3(NT), 0, stream>>>(
      points, feats, out_pts, idx_ws, trans, M, use_t ? 1 : 0);

  if (use_t) {
    gather_t_kernel<<<dim3((BB * M + 3) / 4), dim3(256), 0, stream>>>(
        trans, idx_ws, out_f, M);
  } else {
    gather_kernel<<<dim3(BB * M), dim3(CC), 0, stream>>>(feats, idx_ws, out_f, M);
  }
}